// Round 3
// baseline (597.533 us; speedup 1.0000x reference)
//
#include <hip/hip_runtime.h>
#include <math.h>

#define IN_CH 768
#define OUT_CH 48
#define NB 32
#define HW 3136   // 56*56
#define HW4 784   // HW/4
#define NROWS (NB * IN_CH)  // 24576

// clang-native float4 (HIP's float4 is a class; nontemporal builtin needs this)
typedef float f32x4 __attribute__((ext_vector_type(4)));

// ---------------- Kernel 1: fused global avg+max pool per (b,c) row ----------------
__global__ __launch_bounds__(256) void pool_kernel(const float* __restrict__ in,
                                                   float* __restrict__ avg,
                                                   float* __restrict__ mx) {
    const int row = blockIdx.x;
    const f32x4* p = (const f32x4*)(in + (size_t)row * HW);
    float s = 0.f;
    float m = -INFINITY;
    for (int i = threadIdx.x; i < HW4; i += 256) {
        f32x4 v = p[i];
        s += (v.x + v.y) + (v.z + v.w);
        m = fmaxf(m, fmaxf(fmaxf(v.x, v.y), fmaxf(v.z, v.w)));
    }
    // wave-64 reduce
    for (int off = 32; off; off >>= 1) {
        s += __shfl_down(s, off);
        m = fmaxf(m, __shfl_down(m, off));
    }
    __shared__ float ss[4], sm[4];
    const int lane = threadIdx.x & 63, wv = threadIdx.x >> 6;
    if (lane == 0) { ss[wv] = s; sm[wv] = m; }
    __syncthreads();
    if (threadIdx.x == 0) {
        s = (ss[0] + ss[1]) + (ss[2] + ss[3]);
        m = fmaxf(fmaxf(sm[0], sm[1]), fmaxf(sm[2], sm[3]));
        avg[row] = s * (1.0f / (float)HW);
        mx[row]  = m;
    }
}

// ---------------- Kernel 2: tiny shared MLP + sigmoid -> gate ----------------
// gate[b,c] = sigmoid( (w2 @ relu(w1@avg_b))[c] + (w2 @ relu(w1@mx_b))[c] )
//           = sigmoid( (w2 @ (relu(w1@avg_b) + relu(w1@mx_b)))[c] )   (layer2 linear)
__global__ __launch_bounds__(256) void mlp_kernel(const float* __restrict__ avg,
                                                  const float* __restrict__ mx,
                                                  const float* __restrict__ w1,  // [48,768]
                                                  const float* __restrict__ w2,  // [768,48]
                                                  float* __restrict__ gate) {    // [B*768]
    const int b = blockIdx.x;
    __shared__ float sa[IN_CH], sx[IN_CH];
    __shared__ float hsum[OUT_CH];
    for (int c = threadIdx.x; c < IN_CH; c += 256) {
        sa[c] = avg[b * IN_CH + c];
        sx[c] = mx[b * IN_CH + c];
    }
    __syncthreads();
    const int lane = threadIdx.x & 63, wv = threadIdx.x >> 6;
    // layer 1: 48 outputs, one per wave round-robin (coalesced w1 row reads)
    for (int o = wv; o < OUT_CH; o += 4) {
        const float* wrow = w1 + o * IN_CH;
        float pa = 0.f, px = 0.f;
        for (int c = lane; c < IN_CH; c += 64) {
            float w = wrow[c];
            pa += w * sa[c];
            px += w * sx[c];
        }
        for (int off = 32; off; off >>= 1) {
            pa += __shfl_down(pa, off);
            px += __shfl_down(px, off);
        }
        if (lane == 0) hsum[o] = fmaxf(pa, 0.f) + fmaxf(px, 0.f);
    }
    __syncthreads();
    // layer 2 + sigmoid
    for (int c = threadIdx.x; c < IN_CH; c += 256) {
        const float* wrow = w2 + c * OUT_CH;  // 48 consecutive floats
        float acc = 0.f;
#pragma unroll
        for (int o = 0; o < OUT_CH; ++o) acc += wrow[o] * hsum[o];
        gate[b * IN_CH + c] = 1.0f / (1.0f + expf(-acc));
    }
}

// ---------------- Kernel 3: broadcast-scale each row by its gate ----------------
// Rows processed in REVERSE block order: pool streamed rows 0..NROWS-1, so L3
// holds the tail of the input when this kernel starts — read freshest first.
// Output stores are non-temporal so the 308 MB write stream doesn't evict the
// input we want to re-read from L3.
__global__ __launch_bounds__(256) void scale_kernel(const float* __restrict__ in,
                                                    const float* __restrict__ gate,
                                                    float* __restrict__ out) {
    const int row = NROWS - 1 - blockIdx.x;
    const float g = gate[row];
    const f32x4* p = (const f32x4*)(in + (size_t)row * HW);
    f32x4* q = (f32x4*)(out + (size_t)row * HW);
    for (int i = threadIdx.x; i < HW4; i += 256) {
        f32x4 v = p[i];
        v *= g;
        __builtin_nontemporal_store(v, q + i);
    }
}

extern "C" void kernel_launch(void* const* d_in, const int* in_sizes, int n_in,
                              void* d_out, int out_size, void* d_ws, size_t ws_size,
                              hipStream_t stream) {
    const float* in = (const float*)d_in[0];
    const float* w1 = (const float*)d_in[1];
    const float* w2 = (const float*)d_in[2];
    float* out = (float*)d_out;

    float* avg  = (float*)d_ws;            // [24576]
    float* mx   = avg + NROWS;             // [24576]
    float* gate = mx + NROWS;              // [24576]

    pool_kernel<<<NROWS, 256, 0, stream>>>(in, avg, mx);
    mlp_kernel<<<NB, 256, 0, stream>>>(avg, mx, w1, w2, gate);
    scale_kernel<<<NROWS, 256, 0, stream>>>(in, gate, out);
}